// Round 5
// baseline (83.275 us; speedup 1.0000x reference)
//
#include <hip/hip_runtime.h>
#include <hip/hip_bf16.h>

typedef __attribute__((ext_vector_type(8))) short bf16x8;
typedef __attribute__((ext_vector_type(4))) float f32x4;
typedef __attribute__((ext_vector_type(4))) unsigned short u16x4;

static constexpr int D = 256;
static constexpr float INV_T = 2.0f;                 // 1 / temperature(0.5)
static constexpr float KEXP2 = 2.8853900817779268f;  // 2 * log2(e): exp(2x) = 2^(KEXP2*x)
static constexpr int BM = 256;                       // tile side
static constexpr int BK = 32;                        // K-slice
static constexpr int NKS = D / BK;                   // 8 K-steps
static constexpr int TTILE = 32;                     // 8192 / 256
static constexpr int NBLK = TTILE * (TTILE + 1) / 2; // 528 upper-triangle tiles

__device__ inline unsigned short f2bf(float x) {
    unsigned int u = __builtin_bit_cast(unsigned int, x);
    u += 0x7fffu + ((u >> 16) & 1u);   // round-to-nearest-even
    return (unsigned short)(u >> 16);
}
__device__ inline float bf2f(unsigned short h) {
    unsigned int u = ((unsigned int)h) << 16;
    return __builtin_bit_cast(float, u);
}
__device__ inline float fexp2(float x) {
#if __has_builtin(__builtin_amdgcn_exp2f)
    return __builtin_amdgcn_exp2f(x);
#else
    return exp2f(x);
#endif
}

// Kernel 1: per pair i in [0,B): normalize rows i and i+B to bf16,
// rowsum init = -exp(2*selfdot) (diagonal removal), positive-pair dot ->
// per-block partial (no global atomics).
__global__ void k_norm(const float* __restrict__ zi, const float* __restrict__ zj,
                       unsigned short* __restrict__ zn, float* __restrict__ rowsum,
                       float* __restrict__ pos_partial, int B) {
    __shared__ float red[4];
    const int lane = threadIdx.x & 63;
    const int wv = threadIdx.x >> 6;
    const int i = blockIdx.x * 4 + wv;       // pair index
    if (i < B) {
        float4 vi = reinterpret_cast<const float4*>(zi + (size_t)i * D)[lane];
        float4 vj = reinterpret_cast<const float4*>(zj + (size_t)i * D)[lane];
        float ssi = vi.x * vi.x + vi.y * vi.y + vi.z * vi.z + vi.w * vi.w;
        float ssj = vj.x * vj.x + vj.y * vj.y + vj.z * vj.z + vj.w * vj.w;
#pragma unroll
        for (int off = 32; off >= 1; off >>= 1) {
            ssi += __shfl_xor(ssi, off, 64);
            ssj += __shfl_xor(ssj, off, 64);
        }
        float rni = rsqrtf(ssi), rnj = rsqrtf(ssj);
        unsigned short a0 = f2bf(vi.x * rni), a1 = f2bf(vi.y * rni);
        unsigned short a2 = f2bf(vi.z * rni), a3 = f2bf(vi.w * rni);
        unsigned short b0 = f2bf(vj.x * rnj), b1 = f2bf(vj.y * rnj);
        unsigned short b2 = f2bf(vj.z * rnj), b3 = f2bf(vj.w * rnj);
        u16x4 oa; oa.x = a0; oa.y = a1; oa.z = a2; oa.w = a3;
        u16x4 ob; ob.x = b0; ob.y = b1; ob.z = b2; ob.w = b3;
        *reinterpret_cast<u16x4*>(zn + (size_t)i * D + lane * 4) = oa;
        *reinterpret_cast<u16x4*>(zn + (size_t)(i + B) * D + lane * 4) = ob;
        // self-dots + pair-dot with bf16-rounded values (match MFMA closely)
        float fa0 = bf2f(a0), fa1 = bf2f(a1), fa2 = bf2f(a2), fa3 = bf2f(a3);
        float fb0 = bf2f(b0), fb1 = bf2f(b1), fb2 = bf2f(b2), fb3 = bf2f(b3);
        float sdi = fa0 * fa0 + fa1 * fa1 + fa2 * fa2 + fa3 * fa3;
        float sdj = fb0 * fb0 + fb1 * fb1 + fb2 * fb2 + fb3 * fb3;
        float pd  = fa0 * fb0 + fa1 * fb1 + fa2 * fb2 + fa3 * fb3;
#pragma unroll
        for (int off = 32; off >= 1; off >>= 1) {
            sdi += __shfl_xor(sdi, off, 64);
            sdj += __shfl_xor(sdj, off, 64);
            pd  += __shfl_xor(pd, off, 64);
        }
        if (lane == 0) {
            rowsum[i]     = -fexp2(KEXP2 * sdi);
            rowsum[i + B] = -fexp2(KEXP2 * sdj);
            red[wv] = pd;
        }
    } else if (lane == 0) {
        red[wv] = 0.f;
    }
    __syncthreads();
    if (threadIdx.x == 0)
        pos_partial[blockIdx.x] = 2.0f * INV_T * (red[0] + red[1] + red[2] + red[3]);
}

// Kernel 2: upper-triangle 256x256 sim tiles. 8 waves (2x4), wave owns 128x64.
// A and B K-slices (BK=32) both staged in LDS in MFMA-fragment order,
// double-buffered (64 KB). acc held across all 8 K-steps (128 f32/thread);
// exp + row/col reductions once in the tail. No operand is read from global
// more than once (R3/R4 were L2-bound on per-step A re-fetch).
__global__ __launch_bounds__(512, 2)
void k_main(const unsigned short* __restrict__ zn, float* __restrict__ rowsum, int N) {
    // [buf][panel A=0/B=1][frag rb*64+lane][8 bf16] = 64 KB
    __shared__ __align__(16) unsigned short lds[2][2][1024][8];
    const int tid = threadIdx.x;
    const int lane = tid & 63, wv = tid >> 6;
    const int l15 = lane & 15, lhi = lane >> 4;
    const int wr = wv >> 2, wc = wv & 3;         // wave grid 2 x 4

    // decode upper-triangle tile (ti <= tj)
    int ti = 0, rem = blockIdx.x;
    while (rem >= TTILE - ti) { rem -= TTILE - ti; ++ti; }
    const int tj = ti + rem;
    const bool is_diag = (ti == tj);
    const int i0 = ti * BM, j0 = tj * BM;

    // staging: thread stages panel chunks tid + 512*j (j=0,1) of A and of B.
    // chunk c -> frag rb = c>>6 (16-row group), lane encodes (l15=row, lhi=k8)
    int srow[2];
    const int scol = lhi * 8;
#pragma unroll
    for (int j = 0; j < 2; ++j) srow[j] = ((tid >> 6) + 8 * j) * 16 + l15;

    bf16x8* ldsv = reinterpret_cast<bf16x8*>(lds);

    f32x4 acc[8][4];
#pragma unroll
    for (int r = 0; r < 8; ++r)
#pragma unroll
        for (int c = 0; c < 4; ++c) acc[r][c] = (f32x4){0.f, 0.f, 0.f, 0.f};

    bf16x8 sa[2], sb[2];
    // prologue: stage K-slice 0 into buffer 0 (linear conflict-free writes)
#pragma unroll
    for (int j = 0; j < 2; ++j) {
        sa[j] = *reinterpret_cast<const bf16x8*>(zn + (size_t)(i0 + srow[j]) * D + scol);
        sb[j] = *reinterpret_cast<const bf16x8*>(zn + (size_t)(j0 + srow[j]) * D + scol);
    }
#pragma unroll
    for (int j = 0; j < 2; ++j) {
        ldsv[tid + 512 * j] = sa[j];
        ldsv[1024 + tid + 512 * j] = sb[j];
    }
    __syncthreads();

    for (int ks = 0; ks < NKS; ++ks) {
        const int buf = ks & 1;
        if (ks + 1 < NKS) {   // T14: issue next slice's global loads early
            const int kc = (ks + 1) * BK + scol;
#pragma unroll
            for (int j = 0; j < 2; ++j) {
                sa[j] = *reinterpret_cast<const bf16x8*>(zn + (size_t)(i0 + srow[j]) * D + kc);
                sb[j] = *reinterpret_cast<const bf16x8*>(zn + (size_t)(j0 + srow[j]) * D + kc);
            }
        }
        // fragment reads: linear (lane*16B + imm), conflict-free
        const bf16x8* pa = ldsv + buf * 2048 + wr * 8 * 64;
        const bf16x8* pb = ldsv + buf * 2048 + 1024 + wc * 4 * 64;
        bf16x8 af[8], bfr[4];
#pragma unroll
        for (int r = 0; r < 8; ++r) af[r] = pa[r * 64 + lane];
#pragma unroll
        for (int c = 0; c < 4; ++c) bfr[c] = pb[c * 64 + lane];
#pragma unroll
        for (int r = 0; r < 8; ++r)
#pragma unroll
            for (int c = 0; c < 4; ++c)
                acc[r][c] = __builtin_amdgcn_mfma_f32_16x16x32_bf16(af[r], bfr[c], acc[r][c], 0, 0, 0);

        if (ks + 1 < NKS) {   // write next slice into the other buffer (linear)
#pragma unroll
            for (int j = 0; j < 2; ++j) {
                ldsv[(buf ^ 1) * 2048 + tid + 512 * j] = sa[j];
                ldsv[(buf ^ 1) * 2048 + 1024 + tid + 512 * j] = sb[j];
            }
        }
        __syncthreads();
    }

    // tail: e = exp(2*sim); row-sums always, col-sums for off-diagonal tiles.
    // D-frag mapping (verified R2-R4): col = l15 (+c*16+wc*64), row = lhi*4+q (+r*16+wr*128)
    float cs[4] = {0.f, 0.f, 0.f, 0.f};
#pragma unroll
    for (int r = 0; r < 8; ++r) {
        float rsq[4] = {0.f, 0.f, 0.f, 0.f};
#pragma unroll
        for (int c = 0; c < 4; ++c)
#pragma unroll
            for (int q = 0; q < 4; ++q) {
                float e = fexp2(KEXP2 * acc[r][c][q]);
                rsq[q] += e;
                cs[c] += e;
            }
#pragma unroll
        for (int q = 0; q < 4; ++q) {
            float v = rsq[q];
            v += __shfl_xor(v, 1, 64);
            v += __shfl_xor(v, 2, 64);
            v += __shfl_xor(v, 4, 64);
            v += __shfl_xor(v, 8, 64);
            if (l15 == 0)
                atomicAdd(&rowsum[i0 + wr * 128 + r * 16 + lhi * 4 + q], v);
        }
    }
    if (!is_diag) {
#pragma unroll
        for (int c = 0; c < 4; ++c) {
            float v = cs[c];
            v += __shfl_xor(v, 16, 64);
            v += __shfl_xor(v, 32, 64);
            if (lhi == 0)
                atomicAdd(&rowsum[j0 + wc * 64 + c * 16 + l15], v);
        }
    }
}

// Kernel 3: loss = (sum_i log(rowsum_i) - sum_b pos_partial_b) / N
__global__ void k_final(const float* __restrict__ rowsum, const float* __restrict__ pos_partial,
                        int n_partial, float* __restrict__ out, int N) {
    __shared__ float red[16];
    int lane = threadIdx.x & 63, wv = threadIdx.x >> 6;
    float local = 0.f;
    for (int i = threadIdx.x; i < N; i += 1024) local += __logf(rowsum[i]);
    for (int i = threadIdx.x; i < n_partial; i += 1024) local -= pos_partial[i];
#pragma unroll
    for (int off = 32; off >= 1; off >>= 1) local += __shfl_xor(local, off, 64);
    if (lane == 0) red[wv] = local;
    __syncthreads();
    if (threadIdx.x == 0) {
        float t = 0.f;
#pragma unroll
        for (int w = 0; w < 16; ++w) t += red[w];
        out[0] = t / (float)N;
    }
}

extern "C" void kernel_launch(void* const* d_in, const int* in_sizes, int n_in,
                              void* d_out, int out_size, void* d_ws, size_t ws_size,
                              hipStream_t stream) {
    const float* zi = (const float*)d_in[0];
    const float* zj = (const float*)d_in[1];
    const int B = in_sizes[0] / D;   // 4096
    const int N = 2 * B;             // 8192

    unsigned short* zn = (unsigned short*)d_ws;                       // N*D bf16 = 4 MB
    float* rowsum = (float*)((char*)d_ws + (size_t)N * D * 2);        // N floats
    float* pos_partial = rowsum + N;                                  // B/4 floats

    float* out = (float*)d_out;

    const int npb = B / 4;  // k_norm blocks == pos partials
    hipLaunchKernelGGL(k_norm, dim3(npb), dim3(256), 0, stream, zi, zj, zn, rowsum, pos_partial, B);
    hipLaunchKernelGGL(k_main, dim3(NBLK), dim3(512), 0, stream, zn, rowsum, N);
    hipLaunchKernelGGL(k_final, dim3(1), dim3(1024), 0, stream, rowsum, pos_partial, npb, out, N);
}